// Round 13
// baseline (87.403 us; speedup 1.0000x reference)
//
#include <hip/hip_runtime.h>
#include <hip/hip_bf16.h>

#define NN 4096
#define FF 128
#define IT 16              // rows per block -> grid = 256 = 1 block/CU
#define WC 128             // window cols
#define NWIN (NN / WC)     // 32
#define STRH 136           // sH row stride in u16 (272B, 16B-aligned rows)
#define CAP 24             // edges/row/window cap (Binom(128,.02): P(>=24) ~ 1e-20)

__device__ __forceinline__ float bfhi(unsigned int u) { return __uint_as_float(u & 0xFFFF0000u); }
__device__ __forceinline__ float bflo(unsigned int u) { return __uint_as_float(u << 16); }

// ---------------------------------------------------------------------------
// Detect adjacency encoding from the first 64 KB (R12's scheme: plain stores,
// no memset, no atomics). fmt: 0 = int32, 1 = uint8, 2/3 = float32.
__global__ __launch_bounds__(256) void detect_fmt(const unsigned int* __restrict__ w,
                                                  int* __restrict__ flagParts) {
    __shared__ int s_red[4];
    int t = threadIdx.x;
    unsigned int v = w[blockIdx.x * 256 + t];
    unsigned long long bh = __ballot((v & 0xFFFFFF00u) != 0u);
    unsigned long long bf = __ballot(v == 0x3F800000u);
    int bits = (bh ? 1 : 0) | (bf ? 2 : 0);
    if ((t & 63) == 0) s_red[t >> 6] = bits;
    __syncthreads();
    if (t == 0) flagParts[blockIdx.x] = s_red[0] | s_red[1] | s_red[2] | s_red[3];
}

// ---------------------------------------------------------------------------
// h = x @ W^T -> bf16 hbf ONLY; attn coefficients fused from f32 accumulators.
__global__ __launch_bounds__(256) void gemm_h(const float* __restrict__ x,
                                              const float* __restrict__ W,
                                              const float* __restrict__ a_src,
                                              const float* __restrict__ a_dst,
                                              unsigned short* __restrict__ hbf,
                                              float* __restrict__ asrc,
                                              float* __restrict__ adst) {
    __shared__ float xs[16][FF];
    int r0 = blockIdx.x * 16;
    const float4* xv = (const float4*)(x + (size_t)r0 * FF);
    float4* xsv = (float4*)&xs[0][0];
    for (int t = threadIdx.x; t < 16 * FF / 4; t += 256) xsv[t] = xv[t];
    __syncthreads();

    int c  = threadIdx.x & 127;
    int rr = threadIdx.x >> 7;
    float af = a_src[c];
    float df = a_dst[c];
    float acc[8] = {0.f, 0.f, 0.f, 0.f, 0.f, 0.f, 0.f, 0.f};
    for (int k = 0; k < FF; k += 4) {
        float4 w4 = *(const float4*)&W[(size_t)c * FF + k];
#pragma unroll
        for (int r8 = 0; r8 < 8; ++r8) {
            float4 x4 = *(const float4*)&xs[rr + r8 * 2][k];
            acc[r8] += w4.x * x4.x + w4.y * x4.y + w4.z * x4.z + w4.w * x4.w;
        }
    }
    float ps[8], pd[8];
#pragma unroll
    for (int r8 = 0; r8 < 8; ++r8) {
        union { __hip_bfloat16 b; unsigned short s; } cv;
        cv.b = __float2bfloat16(acc[r8]);
        hbf[(size_t)(r0 + rr + r8 * 2) * FF + c] = cv.s;
        ps[r8] = acc[r8] * af;
        pd[r8] = acc[r8] * df;
    }
#pragma unroll
    for (int m = 1; m <= 16; m <<= 1) {
#pragma unroll
        for (int r8 = 0; r8 < 8; ++r8) {
            ps[r8] += __shfl_xor(ps[r8], m);
            pd[r8] += __shfl_xor(pd[r8], m);
        }
    }
    if ((threadIdx.x & 31) == 0) {
        int hd = c >> 5;
#pragma unroll
        for (int r8 = 0; r8 < 8; ++r8) {
            asrc[(size_t)(r0 + rr + r8 * 2) * 4 + hd] = ps[r8];
            adst[(size_t)(r0 + rr + r8 * 2) * 4 + hd] = pd[r8];
        }
    }
}

// ---------------------------------------------------------------------------
// Windowed LDS-staged aggregation (4th staged attempt; every prior failure
// cause removed: R6 dense-VALU -> sparse edge loop; R7 serial fallback
// compaction -> register-ballot for BOTH formats; R11 big register arrays ->
// rT[4]=16 VGPR + launch_bounds(512,2) cap 256).
// Grid 256 x 512thr; block owns 16 rows; 32 windows of 128 j-cols:
//   SL(w+1): issue coalesced loads to regs (h 32KB, adst 2KB, adj slice)
//   COMPUTE(cur): per-edge all-LDS (idx bcast, adst dword, h b128, 8 fma)
//   SW(w+1): ds_write staging + per-wave 2-row ballot compaction
//   1 barrier/window; sH double-buffered; accumulators persist in regs.
// No max-subtraction: e = s+d ~ N(0,2), exp() far from f32 range.
__global__ __launch_bounds__(512, 2) void gat_win(const unsigned short* __restrict__ hbf,
                                                  const float* __restrict__ asrc,
                                                  const float* __restrict__ adst,
                                                  const void* __restrict__ adj,
                                                  const int* __restrict__ flagParts,
                                                  float* __restrict__ out) {
    __shared__ unsigned short sH[2][WC * STRH];     // 68 KB
    __shared__ float s_adst[2][WC * 4];             // 4 KB
    __shared__ unsigned short s_idx[2][IT][CAP];    // 1.5 KB
    __shared__ int   s_cnt[2][IT];
    __shared__ float s_mac[IT][16][8];              // 8 KB
    __shared__ float s_mden[IT][4];

    const int t      = threadIdx.x;
    const int lane   = t & 63;
    const int lane32 = lane & 31;
    const int i0     = (int)blockIdx.x * IT;

    int fp = flagParts[lane];
    unsigned long long b0 = __ballot((fp & 1) != 0);
    unsigned long long b1 = __ballot((fp & 2) != 0);
    const int fmt = (b0 ? 1 : 0) | (b1 ? 2 : 0);    // 0:int32 1:uint8 2/3:f32

    // compute roles: group g of 16 lanes; 2 groups (halves) per row
    const int g = t >> 4, k = t & 15, row16 = g & 15, half = g >> 4, head = k >> 2;
    const float sA = asrc[(size_t)(i0 + row16) * 4 + head];

    // compaction roles: each wave owns rows 2wv (lanes 0-31), 2wv+1 (32-63)
    const int rowc = t >> 5;                        // == 2*wv + (lane>>5)
    const unsigned int ltm = (1u << lane32) - 1u;

    float a0 = 0.f, a1 = 0.f, a2 = 0.f, a3 = 0.f;
    float a4 = 0.f, a5 = 0.f, a6 = 0.f, a7 = 0.f;
    float den = 0.f;

    uint4 rT[4];            // 16 VGPR staging (R11 used 32+ and blew up)
    uint4 rA4; unsigned int rA1; float rD;

#define SL(w) do {                                                             \
        const int jbs_ = (w) * WC;                                             \
        const uint4* gH_ = (const uint4*)(hbf + (size_t)jbs_ * FF);            \
        _Pragma("unroll")                                                      \
        for (int s_ = 0; s_ < 4; ++s_) rT[s_] = gH_[t + s_ * 512];             \
        rD = (adst + (size_t)jbs_ * 4)[t];                                     \
        if (fmt != 1) {                                                        \
            rA4 = *(const uint4*)((const unsigned int*)adj +                   \
                  (size_t)(i0 + rowc) * NN + jbs_ + lane32 * 4);               \
        } else {                                                               \
            rA1 = *(const unsigned int*)((const unsigned char*)adj +           \
                  (size_t)(i0 + rowc) * NN + jbs_ + lane32 * 4);               \
        }                                                                      \
    } while (0)

#define CW(wk_, kk_, buf) do {                                                 \
        unsigned long long bal_ = __ballot((wk_) != 0u);                       \
        unsigned int mrow_ = (lane < 32) ? (unsigned int)bal_                  \
                                         : (unsigned int)(bal_ >> 32);         \
        int pos_ = myBase + __popc(mrow_ & ltm);                               \
        if ((wk_) && pos_ < CAP)                                               \
            s_idx[buf][rowc][pos_] = (unsigned short)(lane32 * 4 + (kk_));     \
        myBase += __popc(mrow_);                                               \
    } while (0)

#define SW(buf) do {                                                           \
        _Pragma("unroll")                                                      \
        for (int s_ = 0; s_ < 4; ++s_) {                                       \
            int u_ = t + s_ * 512;                                             \
            *(uint4*)&sH[buf][(u_ >> 4) * STRH + (u_ & 15) * 8] = rT[s_];      \
        }                                                                      \
        s_adst[buf][t] = rD;                                                   \
        int myBase = 0;                                                        \
        if (fmt != 1) {                                                        \
            CW(rA4.x, 0, buf); CW(rA4.y, 1, buf);                              \
            CW(rA4.z, 2, buf); CW(rA4.w, 3, buf);                              \
        } else {                                                               \
            CW(rA1 & 0x000000FFu, 0, buf); CW(rA1 & 0x0000FF00u, 1, buf);      \
            CW(rA1 & 0x00FF0000u, 2, buf); CW(rA1 & 0xFF000000u, 3, buf);      \
        }                                                                      \
        if (lane32 == 0) s_cnt[buf][rowc] = min(myBase, CAP);                  \
    } while (0)

#define COMPUTE(buf) do {                                                      \
        int cn_ = s_cnt[buf][row16];                                           \
        for (int e_ = half; e_ < cn_; e_ += 2) {                               \
            int jl_ = s_idx[buf][row16][e_];                                   \
            float dv_ = s_adst[buf][jl_ * 4 + head];                           \
            float ev_ = sA + dv_;                                              \
            ev_ = fmaxf(ev_, 0.2f * ev_);                                      \
            float p_ = __expf(ev_);                                            \
            den += p_;                                                         \
            uint4 hv_ = *(const uint4*)&sH[buf][jl_ * STRH + k * 8];           \
            a0 = fmaf(p_, bflo(hv_.x), a0); a1 = fmaf(p_, bfhi(hv_.x), a1);    \
            a2 = fmaf(p_, bflo(hv_.y), a2); a3 = fmaf(p_, bfhi(hv_.y), a3);    \
            a4 = fmaf(p_, bflo(hv_.z), a4); a5 = fmaf(p_, bfhi(hv_.z), a5);    \
            a6 = fmaf(p_, bflo(hv_.w), a6); a7 = fmaf(p_, bfhi(hv_.w), a7);    \
        }                                                                      \
    } while (0)

    // prologue: window 0 staged
    SL(0);
    SW(0);
    __syncthreads();

    int cur = 0;
    for (int w = 0; w < NWIN; ++w) {
        if (w + 1 < NWIN) SL(w + 1);   // loads in flight during compute
        COMPUTE(cur);
        if (w + 1 < NWIN) SW(cur ^ 1); // implicit vmcnt wait lands here (T14)
        __syncthreads();               // one barrier per window
        cur ^= 1;
    }
#undef SL
#undef CW
#undef SW
#undef COMPUTE

    // ---- merge halves, normalize, write ----
    if (half == 1) {
        float* mp = s_mac[row16][k];
        mp[0] = a0; mp[1] = a1; mp[2] = a2; mp[3] = a3;
        mp[4] = a4; mp[5] = a5; mp[6] = a6; mp[7] = a7;
        if ((k & 3) == 0) s_mden[row16][head] = den;
    }
    __syncthreads();
    if (half == 0) {
        const float* mp = s_mac[row16][k];
        float dtot = den + s_mden[row16][head];
        float rc = (dtot > 0.f) ? 1.f / dtot : 0.f;
        float4 A = {(a0 + mp[0]) * rc, (a1 + mp[1]) * rc,
                    (a2 + mp[2]) * rc, (a3 + mp[3]) * rc};
        float4 B = {(a4 + mp[4]) * rc, (a5 + mp[5]) * rc,
                    (a6 + mp[6]) * rc, (a7 + mp[7]) * rc};
        *(float4*)&out[(size_t)(i0 + row16) * FF + k * 8]     = A;
        *(float4*)&out[(size_t)(i0 + row16) * FF + k * 8 + 4] = B;
    }
}

// ---------------------------------------------------------------------------
extern "C" void kernel_launch(void* const* d_in, const int* in_sizes, int n_in,
                              void* d_out, int out_size, void* d_ws, size_t ws_size,
                              hipStream_t stream) {
    const float* x     = (const float*)d_in[0];
    const void*  adj   = d_in[1];
    const float* W     = (const float*)d_in[2];
    const float* a_src = (const float*)d_in[3];
    const float* a_dst = (const float*)d_in[4];
    float* out = (float*)d_out;

    char* ws = (char*)d_ws;
    unsigned short* hbf   = (unsigned short*)ws;                 // 1 MiB @ 0
    float*          asrc  = (float*)(ws + (1u << 20));           // 64 KiB
    float*          adst  = (float*)(ws + (1u << 20) + 65536);   // 64 KiB
    int*            parts = (int*)  (ws + (1u << 20) + 131072);  // 256 B

    detect_fmt<<<64, 256, 0, stream>>>((const unsigned int*)adj, parts);
    gemm_h    <<<NN / 16, 256, 0, stream>>>(x, W, a_src, a_dst, hbf, asrc, adst);
    gat_win   <<<NN / IT, 512, 0, stream>>>(hbf, asrc, adst, adj, parts, out);
}

// Round 14
// 34.695 us; speedup vs baseline: 2.5192x; 2.5192x over previous
//
#include <hip/hip_runtime.h>
#include <hip/hip_bf16.h>

#define NN 4096
#define FF 128
#define HMAX 192   // per-half edge cap (mean ~41)

__device__ __forceinline__ float bfhi(unsigned int u) { return __uint_as_float(u & 0xFFFF0000u); }
__device__ __forceinline__ float bflo(unsigned int u) { return __uint_as_float(u << 16); }

// ---------------------------------------------------------------------------
// h = x @ W^T -> bf16 hbf ONLY; attn coefficients fused from f32 accumulators.
// Blocks 0..63 ALSO detect the adjacency encoding from its first 64 KB
// (per-wave ballot -> plain store, no atomics/memset; R8 lesson: FETCH_SIZE
// cannot distinguish formats, only runtime detection is trustworthy).
__global__ __launch_bounds__(256) void gemm_h(const float* __restrict__ x,
                                              const float* __restrict__ W,
                                              const float* __restrict__ a_src,
                                              const float* __restrict__ a_dst,
                                              const unsigned int* __restrict__ adjw,
                                              unsigned short* __restrict__ hbf,
                                              float* __restrict__ asrc,
                                              float* __restrict__ adst,
                                              int* __restrict__ parts) {
    if (blockIdx.x < 64) {     // fused format detection (1 KB per block)
        unsigned int v = adjw[blockIdx.x * 256 + threadIdx.x];
        unsigned long long bh = __ballot((v & 0xFFFFFF00u) != 0u);
        unsigned long long bf = __ballot(v == 0x3F800000u);
        if ((threadIdx.x & 63) == 0)
            parts[blockIdx.x * 4 + (threadIdx.x >> 6)] = (bh ? 1 : 0) | (bf ? 2 : 0);
    }

    __shared__ float xs[16][FF];
    int r0 = blockIdx.x * 16;
    const float4* xv = (const float4*)(x + (size_t)r0 * FF);
    float4* xsv = (float4*)&xs[0][0];
    for (int t = threadIdx.x; t < 16 * FF / 4; t += 256) xsv[t] = xv[t];
    __syncthreads();

    int c  = threadIdx.x & 127;
    int rr = threadIdx.x >> 7;
    float af = a_src[c];          // [HEADS][D] flat == [c]
    float df = a_dst[c];
    float acc[8] = {0.f, 0.f, 0.f, 0.f, 0.f, 0.f, 0.f, 0.f};
    for (int k = 0; k < FF; k += 4) {
        float4 w4 = *(const float4*)&W[(size_t)c * FF + k];
#pragma unroll
        for (int r8 = 0; r8 < 8; ++r8) {
            float4 x4 = *(const float4*)&xs[rr + r8 * 2][k];
            acc[r8] += w4.x * x4.x + w4.y * x4.y + w4.z * x4.z + w4.w * x4.w;
        }
    }
    float ps[8], pd[8];
#pragma unroll
    for (int r8 = 0; r8 < 8; ++r8) {
        union { __hip_bfloat16 b; unsigned short s; } cv;
        cv.b = __float2bfloat16(acc[r8]);
        hbf[(size_t)(r0 + rr + r8 * 2) * FF + c] = cv.s;
        ps[r8] = acc[r8] * af;
        pd[r8] = acc[r8] * df;
    }
#pragma unroll
    for (int m = 1; m <= 16; m <<= 1) {     // reduce within each 32-lane head group
#pragma unroll
        for (int r8 = 0; r8 < 8; ++r8) {
            ps[r8] += __shfl_xor(ps[r8], m);
            pd[r8] += __shfl_xor(pd[r8], m);
        }
    }
    if ((threadIdx.x & 31) == 0) {
        int hd = c >> 5;
#pragma unroll
        for (int r8 = 0; r8 < 8; ++r8) {
            asrc[(size_t)(r0 + rr + r8 * 2) * 4 + hd] = ps[r8];
            adst[(size_t)(r0 + rr + r8 * 2) * 4 + hd] = pd[r8];
        }
    }
}

// ---------------------------------------------------------------------------
// R12's proven gather kernel. 4 rows/block, 2 waves/row; register-preloaded
// ballot compaction (both formats); 2-stage pipelined fused aggregation.
// R14 change: NO barrier between compaction and aggregation — each wave
// writes/reads only its own s_idx list, so waves run free until the end-merge
// (audited: only s_mac/s_mden cross waves, and that barrier remains).
// At the per-CU miss-concurrency ceiling (~5.3k lines/CU x ~14cy) — the
// structural floor of the gather formulation (R4/5/8/9/12 evidence).
__global__ __launch_bounds__(512, 8) void gat_agg(const unsigned short* __restrict__ hbf,
                                                  const float* __restrict__ asrc,
                                                  const float* __restrict__ adst,
                                                  const void* __restrict__ adj,
                                                  const int* __restrict__ flagParts,
                                                  float* __restrict__ out) {
    __shared__ int   s_idx[4][2][HMAX + 16];
    __shared__ float s_mac[4][16][8];
    __shared__ float s_mden[4][4];

    int lane = threadIdx.x & 63;
    int wv   = threadIdx.x >> 6;     // 0..7
    int r    = wv >> 1;              // row within block
    int side = wv & 1;               // adjacency half
    int i    = blockIdx.x * 4 + r;

    int4 fp4 = ((const int4*)flagParts)[lane];     // 256 parts, 4 per lane
    int fp = fp4.x | fp4.y | fp4.z | fp4.w;
    unsigned long long b0 = __ballot((fp & 1) != 0);
    unsigned long long b1 = __ballot((fp & 2) != 0);
    int fmt = (b0 ? 1 : 0) | (b1 ? 2 : 0);   // 0:int32 1:uint8 2/3:float32

    int* idx = s_idx[r][side];
    unsigned long long lt = (1ull << lane) - 1ull;

    // ---- Pass A: compact this half's neighbor indices ----
    int base = 0;
    if (fmt != 1) {
        // 4-byte elements (int32 or float32): word != 0 <=> edge
        const uint4* arow4 = (const uint4*)((const unsigned int*)adj +
                             (size_t)i * NN + side * 2048);
        uint4 vb[8];
#pragma unroll
        for (int it = 0; it < 8; ++it) vb[it] = arow4[it * 64 + lane];  // all in flight
#pragma unroll
        for (int it = 0; it < 8; ++it) {
            unsigned int w0 = vb[it].x, w1 = vb[it].y, w2 = vb[it].z, w3 = vb[it].w;
            unsigned long long m0 = __ballot(w0 != 0u);
            unsigned long long m1 = __ballot(w1 != 0u);
            unsigned long long m2 = __ballot(w2 != 0u);
            unsigned long long m3 = __ballot(w3 != 0u);
            int c0 = __popcll(m0), c1 = __popcll(m1), c2 = __popcll(m2);
            int p0 = base + __popcll(m0 & lt);
            int p1 = base + c0 + __popcll(m1 & lt);
            int p2 = base + c0 + c1 + __popcll(m2 & lt);
            int p3 = base + c0 + c1 + c2 + __popcll(m3 & lt);
            int jb = side * 2048 + it * 256 + lane * 4;
            if (w0 && p0 < HMAX) idx[p0] = jb;
            if (w1 && p1 < HMAX) idx[p1] = jb + 1;
            if (w2 && p2 < HMAX) idx[p2] = jb + 2;
            if (w3 && p3 < HMAX) idx[p3] = jb + 3;
            base += c0 + c1 + c2 + __popcll(m3);
        }
    } else {
        // uint8 (numpy bool)
        const unsigned int* arow =
            (const unsigned int*)((const unsigned char*)adj + (size_t)i * NN + side * 2048);
        unsigned int vb[8];
#pragma unroll
        for (int it = 0; it < 8; ++it) vb[it] = arow[it * 64 + lane];
#pragma unroll
        for (int it = 0; it < 8; ++it) {
            unsigned int v = vb[it];
            unsigned long long m0 = __ballot((v & 0x000000FFu) != 0u);
            unsigned long long m1 = __ballot((v & 0x0000FF00u) != 0u);
            unsigned long long m2 = __ballot((v & 0x00FF0000u) != 0u);
            unsigned long long m3 = __ballot((v & 0xFF000000u) != 0u);
            int c0 = __popcll(m0), c1 = __popcll(m1), c2 = __popcll(m2);
            int p0 = base + __popcll(m0 & lt);
            int p1 = base + c0 + __popcll(m1 & lt);
            int p2 = base + c0 + c1 + __popcll(m2 & lt);
            int p3 = base + c0 + c1 + c2 + __popcll(m3 & lt);
            int jb = side * 2048 + it * 256 + lane * 4;
            if ((v & 0x000000FFu) && p0 < HMAX) idx[p0] = jb;
            if ((v & 0x0000FF00u) && p1 < HMAX) idx[p1] = jb + 1;
            if ((v & 0x00FF0000u) && p2 < HMAX) idx[p2] = jb + 2;
            if ((v & 0xFF000000u) && p3 < HMAX) idx[p3] = jb + 3;
            base += c0 + c1 + c2 + __popcll(m3);
        }
    }
    int cnt = min(base, HMAX);
    if (lane < 16) idx[cnt + lane] = i;   // pads; weight forced to 0 by e<cnt
    // NOTE: no __syncthreads() here (R14) — this wave only reads its own idx.

    // ---- Fused aggregation + denominator, 2-stage pipelined ----
    int q    = lane >> 4;             // edge slot within batch of 4
    int k    = lane & 15;             // features 8k .. 8k+7
    int head = k >> 2;
    float sA = asrc[(i << 2) + head];
    const uint4* hb4 = (const uint4*)hbf;

    float a0 = 0.f, a1 = 0.f, a2 = 0.f, a3 = 0.f;
    float a4 = 0.f, a5 = 0.f, a6 = 0.f, a7 = 0.f;
    float den = 0.f;
    int cntPad = (cnt + 7) & ~7;

#define PROC(HV, DV, E) do {                                                   \
        float ev_ = sA + (DV);                                                 \
        ev_ = fmaxf(ev_, 0.2f * ev_);                                          \
        float p_ = __expf(ev_);                                                \
        p_ = ((E) < cnt) ? p_ : 0.f;                                           \
        den += p_;                                                             \
        a0 = fmaf(p_, bflo((HV).x), a0); a1 = fmaf(p_, bfhi((HV).x), a1);      \
        a2 = fmaf(p_, bflo((HV).y), a2); a3 = fmaf(p_, bfhi((HV).y), a3);      \
        a4 = fmaf(p_, bflo((HV).z), a4); a5 = fmaf(p_, bfhi((HV).z), a5);      \
        a6 = fmaf(p_, bflo((HV).w), a6); a7 = fmaf(p_, bfhi((HV).w), a7);      \
    } while (0)

    // prologue: issue batch 0 (pads make idx[0..15] always valid)
    int e0 = q, e1 = 4 + q;
    int j0 = idx[e0], j1 = idx[e1];
    uint4 hv0 = hb4[(size_t)j0 * 16 + k];
    uint4 hv1 = hb4[(size_t)j1 * 16 + k];
    float dv0 = adst[(j0 << 2) + head];
    float dv1 = adst[(j1 << 2) + head];

    for (int eb = 0; eb < cntPad; eb += 8) {
        int   ce0 = e0,  ce1 = e1;
        uint4 chv0 = hv0, chv1 = hv1;
        float cdv0 = dv0, cdv1 = dv1;
        if (eb + 8 < cntPad) {        // wave-uniform: issue NEXT batch now
            e0 = eb + 8 + q; e1 = eb + 12 + q;
            int nj0 = idx[e0], nj1 = idx[e1];
            hv0 = hb4[(size_t)nj0 * 16 + k];
            hv1 = hb4[(size_t)nj1 * 16 + k];
            dv0 = adst[(nj0 << 2) + head];
            dv1 = adst[(nj1 << 2) + head];
        }
        PROC(chv0, cdv0, ce0);        // consume current while next is in flight
        PROC(chv1, cdv1, ce1);
    }
#undef PROC

    // merge the 4 edge-quarters (lanes differing in bits 4,5 share k)
#pragma unroll
    for (int m = 16; m <= 32; m <<= 1) {
        a0 += __shfl_xor(a0, m); a1 += __shfl_xor(a1, m);
        a2 += __shfl_xor(a2, m); a3 += __shfl_xor(a3, m);
        a4 += __shfl_xor(a4, m); a5 += __shfl_xor(a5, m);
        a6 += __shfl_xor(a6, m); a7 += __shfl_xor(a7, m);
        den += __shfl_xor(den, m);
    }

    if (side == 1 && lane < 16) {
        float* mp = s_mac[r][k];
        mp[0] = a0; mp[1] = a1; mp[2] = a2; mp[3] = a3;
        mp[4] = a4; mp[5] = a5; mp[6] = a6; mp[7] = a7;
        if ((k & 3) == 0) s_mden[r][head] = den;
    }
    __syncthreads();                   // required: cross-wave merge
    if (side == 0 && lane < 16) {
        const float* mp = s_mac[r][k];
        float dtot = den + s_mden[r][head];
        float rc = (dtot > 0.f) ? 1.f / dtot : 0.f;
        float4 A = {(a0 + mp[0]) * rc, (a1 + mp[1]) * rc,
                    (a2 + mp[2]) * rc, (a3 + mp[3]) * rc};
        float4 B = {(a4 + mp[4]) * rc, (a5 + mp[5]) * rc,
                    (a6 + mp[6]) * rc, (a7 + mp[7]) * rc};
        *(float4*)&out[(size_t)i * FF + k * 8]     = A;
        *(float4*)&out[(size_t)i * FF + k * 8 + 4] = B;
    }
}

// ---------------------------------------------------------------------------
extern "C" void kernel_launch(void* const* d_in, const int* in_sizes, int n_in,
                              void* d_out, int out_size, void* d_ws, size_t ws_size,
                              hipStream_t stream) {
    const float* x     = (const float*)d_in[0];
    const void*  adj   = d_in[1];
    const float* W     = (const float*)d_in[2];
    const float* a_src = (const float*)d_in[3];
    const float* a_dst = (const float*)d_in[4];
    float* out = (float*)d_out;

    char* ws = (char*)d_ws;
    unsigned short* hbf   = (unsigned short*)ws;                 // 1 MiB @ 0
    float*          asrc  = (float*)(ws + (1u << 20));           // 64 KiB
    float*          adst  = (float*)(ws + (1u << 20) + 65536);   // 64 KiB
    int*            parts = (int*)  (ws + (1u << 20) + 131072);  // 1 KiB

    gemm_h <<<NN / 16, 256, 0, stream>>>(x, W, a_src, a_dst,
                                         (const unsigned int*)adj,
                                         hbf, asrc, adst, parts);
    gat_agg<<<NN / 4, 512, 0, stream>>>(hbf, asrc, adst, adj, parts, out);
}